// Round 1
// baseline (260.558 us; speedup 1.0000x reference)
//
#include <hip/hip_runtime.h>
#include <stdint.h>

typedef int v4i __attribute__((ext_vector_type(4)));

#define EPS_F32 1.1920928955078125e-07f   // np.finfo(float32).eps = 2^-23

// ---------------------------------------------------------------------------
// Kernel 1: per-token activation quant.
// Xs = X / ss ; x_scale = max(absmax(Xs), 1e-5)/127 ; Xq = clip(rint(Xs/x_scale), -127, 127)
// one block (256 thr) per token row of DIN=4096.
// ---------------------------------------------------------------------------
__global__ __launch_bounds__(256) void xquant_kernel(
    const float* __restrict__ X, const float* __restrict__ ss,
    int8_t* __restrict__ Xq, float* __restrict__ xs, int DIN)
{
    const int t   = blockIdx.x;
    const int tid = threadIdx.x;
    const float* xrow = X + (size_t)t * DIN;

    float4 v[4];
    float amax = 0.f;
#pragma unroll
    for (int c = 0; c < 4; ++c) {
        const int k = c * 1024 + tid * 4;
        float4 xv = *(const float4*)(xrow + k);
        float4 sv = *(const float4*)(ss + k);
        float4 q;
        q.x = xv.x / sv.x; q.y = xv.y / sv.y;
        q.z = xv.z / sv.z; q.w = xv.w / sv.w;
        v[c] = q;
        amax = fmaxf(amax, fmaxf(fmaxf(fabsf(q.x), fabsf(q.y)),
                                 fmaxf(fabsf(q.z), fabsf(q.w))));
    }
    // block-wide max reduce
    __shared__ float red[4];
    for (int off = 32; off; off >>= 1) amax = fmaxf(amax, __shfl_xor(amax, off));
    const int lane = tid & 63, w = tid >> 6;
    if (lane == 0) red[w] = amax;
    __syncthreads();
    amax = fmaxf(fmaxf(red[0], red[1]), fmaxf(red[2], red[3]));

    const float scale = fmaxf(amax, 1e-5f) / 127.0f;
    if (tid == 0) xs[t] = scale;

    int* qout = (int*)(Xq + (size_t)t * DIN);
#pragma unroll
    for (int c = 0; c < 4; ++c) {
        float4 q = v[c];
        int b0 = (int)fminf(fmaxf(rintf(q.x / scale), -127.f), 127.f);
        int b1 = (int)fminf(fmaxf(rintf(q.y / scale), -127.f), 127.f);
        int b2 = (int)fminf(fmaxf(rintf(q.z / scale), -127.f), 127.f);
        int b3 = (int)fminf(fmaxf(rintf(q.w / scale), -127.f), 127.f);
        qout[c * 256 + tid] = (b0 & 255) | ((b1 & 255) << 8) |
                              ((b2 & 255) << 16) | ((b3 & 255) << 24);
    }
}

// ---------------------------------------------------------------------------
// Kernel 2: per-out-channel weight quant.
// Ws = W[o,:]*ss ; w_scale = max(absmax/127.5, EPS) ; Wq = clip(rint(Ws/w_scale), -128, 127)
// ---------------------------------------------------------------------------
__global__ __launch_bounds__(256) void wquant_kernel(
    const float* __restrict__ W, const float* __restrict__ ss,
    int8_t* __restrict__ Wq, float* __restrict__ ws, int DIN)
{
    const int o   = blockIdx.x;
    const int tid = threadIdx.x;
    const float* wrow = W + (size_t)o * DIN;

    float4 v[4];
    float amax = 0.f;
#pragma unroll
    for (int c = 0; c < 4; ++c) {
        const int k = c * 1024 + tid * 4;
        float4 wv = *(const float4*)(wrow + k);
        float4 sv = *(const float4*)(ss + k);
        float4 q;
        q.x = wv.x * sv.x; q.y = wv.y * sv.y;
        q.z = wv.z * sv.z; q.w = wv.w * sv.w;
        v[c] = q;
        amax = fmaxf(amax, fmaxf(fmaxf(fabsf(q.x), fabsf(q.y)),
                                 fmaxf(fabsf(q.z), fabsf(q.w))));
    }
    __shared__ float red[4];
    for (int off = 32; off; off >>= 1) amax = fmaxf(amax, __shfl_xor(amax, off));
    const int lane = tid & 63, w = tid >> 6;
    if (lane == 0) red[w] = amax;
    __syncthreads();
    amax = fmaxf(fmaxf(red[0], red[1]), fmaxf(red[2], red[3]));

    const float scale = fmaxf(amax / 127.5f, EPS_F32);
    if (tid == 0) ws[o] = scale;

    int* qout = (int*)(Wq + (size_t)o * DIN);
#pragma unroll
    for (int c = 0; c < 4; ++c) {
        float4 q = v[c];
        int b0 = (int)fminf(fmaxf(rintf(q.x / scale), -128.f), 127.f);
        int b1 = (int)fminf(fmaxf(rintf(q.y / scale), -128.f), 127.f);
        int b2 = (int)fminf(fmaxf(rintf(q.z / scale), -128.f), 127.f);
        int b3 = (int)fminf(fmaxf(rintf(q.w / scale), -128.f), 127.f);
        qout[c * 256 + tid] = (b0 & 255) | ((b1 & 255) << 8) |
                              ((b2 & 255) << 16) | ((b3 & 255) << 24);
    }
}

// ---------------------------------------------------------------------------
// Kernel 3: int8 NT GEMM  acc[m,n] = sum_k Xq[m,k]*Wq[n,k]  (exact int32)
// fused dequant: Y = acc * xs[m] * ws[n] + bias[n]
// 128x128 tile, BK=64 bytes, 4 waves (2x2 of 64x64), mfma_i32_16x16x64_i8.
// LDS chunk-XOR swizzle (c ^= (r>>1)&3) applied on BOTH the global source of
// global_load_lds and the ds_read side (rule: both-sides-or-neither).
// ---------------------------------------------------------------------------
#define BM 128
#define BN 128
#define BK 64

__global__ __launch_bounds__(256) void gemm_i8_kernel(
    const int8_t* __restrict__ Xq, const int8_t* __restrict__ Wq,
    const float* __restrict__ xs, const float* __restrict__ ws,
    const float* __restrict__ bias, float* __restrict__ Y,
    int M, int N, int K)
{
    __shared__ __align__(16) int8_t As[BM * BK];
    __shared__ __align__(16) int8_t Bs[BN * BK];

    const int tid  = threadIdx.x;
    const int lane = tid & 63;
    const int w    = tid >> 6;
    const int nbn  = N / BN;
    const int bn   = blockIdx.x % nbn;
    const int bm   = blockIdx.x / nbn;

    const int8_t* aBase = Xq + (size_t)bm * BM * K;
    const int8_t* bBase = Wq + (size_t)bn * BN * K;

    // staging: thread covers 16B chunks flat = tid and 256+tid of the 128x64B tile.
    // LDS dest is linear (wave-uniform base + lane*16); global source is
    // pre-swizzled so that LDS (r,c) holds logical chunk c ^ ((r>>1)&3).
    const int r0 = tid >> 2,        c0 = tid & 3;
    const int r1 = (256 + tid) >> 2, c1 = tid & 3;
    const size_t aoff0 = (size_t)r0 * K + ((c0 ^ ((r0 >> 1) & 3)) << 4);
    const size_t aoff1 = (size_t)r1 * K + ((c1 ^ ((r1 >> 1) & 3)) << 4);

    // fragment read addresses (swizzled): logical chunk = lane>>4
    const int wrow = w >> 1, wcol = w & 1;
    const int ar = wrow * 64 + (lane & 15);
    const int br = wcol * 64 + (lane & 15);
    const int ac = lane >> 4;
    const int aoffL = ar * 64 + ((ac ^ ((ar >> 1) & 3)) << 4);
    const int boffL = br * 64 + ((ac ^ ((br >> 1) & 3)) << 4);

    v4i acc[4][4] = {};

    const int KT = K / BK;
    for (int kt = 0; kt < KT; ++kt) {
        const int8_t* aS = aBase + kt * BK;
        const int8_t* bS = bBase + kt * BK;
        __builtin_amdgcn_global_load_lds(
            (const __attribute__((address_space(1))) void*)(aS + aoff0),
            (__attribute__((address_space(3))) void*)(As + w * 1024), 16, 0, 0);
        __builtin_amdgcn_global_load_lds(
            (const __attribute__((address_space(1))) void*)(aS + aoff1),
            (__attribute__((address_space(3))) void*)(As + 4096 + w * 1024), 16, 0, 0);
        __builtin_amdgcn_global_load_lds(
            (const __attribute__((address_space(1))) void*)(bS + aoff0),
            (__attribute__((address_space(3))) void*)(Bs + w * 1024), 16, 0, 0);
        __builtin_amdgcn_global_load_lds(
            (const __attribute__((address_space(1))) void*)(bS + aoff1),
            (__attribute__((address_space(3))) void*)(Bs + 4096 + w * 1024), 16, 0, 0);
        __syncthreads();

        v4i a[4], b[4];
#pragma unroll
        for (int i = 0; i < 4; ++i)
            a[i] = *(const v4i*)(As + aoffL + i * 1024);
#pragma unroll
        for (int j = 0; j < 4; ++j)
            b[j] = *(const v4i*)(Bs + boffL + j * 1024);
#pragma unroll
        for (int i = 0; i < 4; ++i)
#pragma unroll
            for (int j = 0; j < 4; ++j)
                acc[i][j] = __builtin_amdgcn_mfma_i32_16x16x64_i8(a[i], b[j], acc[i][j], 0, 0, 0);
        __syncthreads();
    }

    // epilogue: C/D layout col=lane&15, row=(lane>>4)*4+reg  (dtype-independent, m121-m128)
    const int rowb = (lane >> 4) * 4;
    const int col  = lane & 15;
    float xsv[4][4];
#pragma unroll
    for (int i = 0; i < 4; ++i)
#pragma unroll
        for (int r = 0; r < 4; ++r)
            xsv[i][r] = xs[bm * BM + wrow * 64 + i * 16 + rowb + r];
    float wsv[4], bv[4];
#pragma unroll
    for (int j = 0; j < 4; ++j) {
        const int n = bn * BN + wcol * 64 + j * 16 + col;
        wsv[j] = ws[n];
        bv[j]  = bias[n];
    }
#pragma unroll
    for (int i = 0; i < 4; ++i) {
#pragma unroll
        for (int r = 0; r < 4; ++r) {
            const size_t m = (size_t)bm * BM + wrow * 64 + i * 16 + rowb + r;
            float* yrow = Y + m * N;
#pragma unroll
            for (int j = 0; j < 4; ++j) {
                const int n = bn * BN + wcol * 64 + j * 16 + col;
                yrow[n] = (float)acc[i][j][r] * xsv[i][r] * wsv[j] + bv[j];
            }
        }
    }
}

// ---------------------------------------------------------------------------
extern "C" void kernel_launch(void* const* d_in, const int* in_sizes, int n_in,
                              void* d_out, int out_size, void* d_ws, size_t ws_size,
                              hipStream_t stream) {
    const float* X    = (const float*)d_in[0];
    const float* W    = (const float*)d_in[1];
    const float* bias = (const float*)d_in[2];
    const float* ss   = (const float*)d_in[3];

    const int DIN  = in_sizes[3];              // 4096
    const int DOUT = in_sizes[2];              // 4096
    const int M    = in_sizes[0] / DIN;        // 8192

    int8_t* Xq = (int8_t*)d_ws;
    int8_t* Wq = Xq + (size_t)M * DIN;
    float*  xs = (float*)(Wq + (size_t)DOUT * DIN);
    float*  ws = xs + M;
    float*  Y  = (float*)d_out;

    xquant_kernel<<<M,    256, 0, stream>>>(X, ss, Xq, xs, DIN);
    wquant_kernel<<<DOUT, 256, 0, stream>>>(W, ss, Wq, ws, DIN);
    gemm_i8_kernel<<<(M / BM) * (DOUT / BN), 256, 0, stream>>>(Xq, Wq, xs, ws, bias, Y, M, DOUT, DIN);
}

// Round 2
// 189.367 us; speedup vs baseline: 1.3759x; 1.3759x over previous
//
#include <hip/hip_runtime.h>
#include <stdint.h>

typedef int v4i __attribute__((ext_vector_type(4)));

#define EPS_F32 1.1920928955078125e-07f   // np.finfo(float32).eps = 2^-23

// ---------------------------------------------------------------------------
// Kernel 1: per-token activation quant.
// ---------------------------------------------------------------------------
__global__ __launch_bounds__(256) void xquant_kernel(
    const float* __restrict__ X, const float* __restrict__ ss,
    int8_t* __restrict__ Xq, float* __restrict__ xs, int DIN)
{
    const int t   = blockIdx.x;
    const int tid = threadIdx.x;
    const float* xrow = X + (size_t)t * DIN;

    float4 v[4];
    float amax = 0.f;
#pragma unroll
    for (int c = 0; c < 4; ++c) {
        const int k = c * 1024 + tid * 4;
        float4 xv = *(const float4*)(xrow + k);
        float4 sv = *(const float4*)(ss + k);
        float4 q;
        q.x = xv.x / sv.x; q.y = xv.y / sv.y;
        q.z = xv.z / sv.z; q.w = xv.w / sv.w;
        v[c] = q;
        amax = fmaxf(amax, fmaxf(fmaxf(fabsf(q.x), fabsf(q.y)),
                                 fmaxf(fabsf(q.z), fabsf(q.w))));
    }
    __shared__ float red[4];
    for (int off = 32; off; off >>= 1) amax = fmaxf(amax, __shfl_xor(amax, off));
    const int lane = tid & 63, w = tid >> 6;
    if (lane == 0) red[w] = amax;
    __syncthreads();
    amax = fmaxf(fmaxf(red[0], red[1]), fmaxf(red[2], red[3]));

    const float scale = fmaxf(amax, 1e-5f) / 127.0f;
    if (tid == 0) xs[t] = scale;

    int* qout = (int*)(Xq + (size_t)t * DIN);
#pragma unroll
    for (int c = 0; c < 4; ++c) {
        float4 q = v[c];
        int b0 = (int)fminf(fmaxf(rintf(q.x / scale), -127.f), 127.f);
        int b1 = (int)fminf(fmaxf(rintf(q.y / scale), -127.f), 127.f);
        int b2 = (int)fminf(fmaxf(rintf(q.z / scale), -127.f), 127.f);
        int b3 = (int)fminf(fmaxf(rintf(q.w / scale), -127.f), 127.f);
        qout[c * 256 + tid] = (b0 & 255) | ((b1 & 255) << 8) |
                              ((b2 & 255) << 16) | ((b3 & 255) << 24);
    }
}

// ---------------------------------------------------------------------------
// Kernel 2: per-out-channel weight quant.
// ---------------------------------------------------------------------------
__global__ __launch_bounds__(256) void wquant_kernel(
    const float* __restrict__ W, const float* __restrict__ ss,
    int8_t* __restrict__ Wq, float* __restrict__ ws, int DIN)
{
    const int o   = blockIdx.x;
    const int tid = threadIdx.x;
    const float* wrow = W + (size_t)o * DIN;

    float4 v[4];
    float amax = 0.f;
#pragma unroll
    for (int c = 0; c < 4; ++c) {
        const int k = c * 1024 + tid * 4;
        float4 wv = *(const float4*)(wrow + k);
        float4 sv = *(const float4*)(ss + k);
        float4 q;
        q.x = wv.x * sv.x; q.y = wv.y * sv.y;
        q.z = wv.z * sv.z; q.w = wv.w * sv.w;
        v[c] = q;
        amax = fmaxf(amax, fmaxf(fmaxf(fabsf(q.x), fabsf(q.y)),
                                 fmaxf(fabsf(q.z), fabsf(q.w))));
    }
    __shared__ float red[4];
    for (int off = 32; off; off >>= 1) amax = fmaxf(amax, __shfl_xor(amax, off));
    const int lane = tid & 63, w = tid >> 6;
    if (lane == 0) red[w] = amax;
    __syncthreads();
    amax = fmaxf(fmaxf(red[0], red[1]), fmaxf(red[2], red[3]));

    const float scale = fmaxf(amax / 127.5f, EPS_F32);
    if (tid == 0) ws[o] = scale;

    int* qout = (int*)(Wq + (size_t)o * DIN);
#pragma unroll
    for (int c = 0; c < 4; ++c) {
        float4 q = v[c];
        int b0 = (int)fminf(fmaxf(rintf(q.x / scale), -128.f), 127.f);
        int b1 = (int)fminf(fmaxf(rintf(q.y / scale), -128.f), 127.f);
        int b2 = (int)fminf(fmaxf(rintf(q.z / scale), -128.f), 127.f);
        int b3 = (int)fminf(fmaxf(rintf(q.w / scale), -128.f), 127.f);
        qout[c * 256 + tid] = (b0 & 255) | ((b1 & 255) << 8) |
                              ((b2 & 255) << 16) | ((b3 & 255) << 24);
    }
}

// ---------------------------------------------------------------------------
// Kernel 3: int8 NT GEMM, 256x256 tile, BK=128 bytes, 8-phase schedule
// (T2 LDS XOR-swizzle + T3/T4 counted vmcnt + T5 setprio), 8 waves (2x4),
// 128 KiB double-buffered LDS, mfma_i32_16x16x64_i8.
//
// Wave (wrow,wcol) owns rows {ih*128 + wrow*64 + (i&3)*16} x cols
// {jh*128 + wcol*32 + (j&1)*16}, so half-tiles are 128 contiguous rows.
// Half-tile issue order per K-tile: hA0, hB0, hB1, hA1 (one per phase).
// Phase needs:   P0: hA0+hB0   P1: hB1   P2: hA1   P3: -
// vmcnt(4) at P0/P1/P3 closings lands exactly the next phase's half-tile.
// LDS swizzle: phys chunk c holds logical chunk c ^ (row&7); applied on the
// global source of global_load_lds and on the ds_read address (rule #21).
// ---------------------------------------------------------------------------
#define BM 256
#define BN 256
#define BKB 128

#define MFMA __builtin_amdgcn_mfma_i32_16x16x64_i8

__global__ __launch_bounds__(512, 2) void gemm_i8_kernel(
    const int8_t* __restrict__ Xq, const int8_t* __restrict__ Wq,
    const float* __restrict__ xs, const float* __restrict__ ws,
    const float* __restrict__ bias, float* __restrict__ Y,
    int M, int N, int K)
{
    __shared__ __align__(16) int8_t smem[131072];

    const int tid  = threadIdx.x;
    const int lane = tid & 63;
    const int w    = tid >> 6;
    const int wrow = w >> 2, wcol = w & 3;

    // XCD-aware swizzle: 512 blocks, 8 XCDs, each XCD gets an 8x8 tile rect.
    const int bid = blockIdx.x;
    const int xcd = bid & 7, idx = bid >> 3;
    const int bm = (xcd >> 1) * 8 + (idx >> 3);   // [0,32)
    const int bn = (xcd & 1) * 8 + (idx & 7);     // [0,16)

    const int8_t* aT0 = Xq + (size_t)bm * BM * K;
    const int8_t* bT0 = Wq + (size_t)bn * BN * K;

    const int srcSwz = ((lane & 7) ^ (lane >> 3)) << 4;  // staging source swizzle
    const int chnk0  = ((lane >> 4) ^ (lane & 7)) << 4;  // frag read, k-slice 0
    const int chnk1  = chnk0 ^ 64;                       // k-slice 1
    const int aRB = ((wrow << 6) + (lane & 15)) << 7;    // A frag row-byte base
    const int bRB = ((wcol << 5) + (lane & 15)) << 7;    // B frag row-byte base

    auto STAGE = [&](const int8_t* gtile, int region, int rowStart) {
        const int8_t* src = gtile +
            (size_t)(rowStart + (w << 3) + (lane >> 3)) * K + srcSwz;
        __builtin_amdgcn_global_load_lds(
            (const __attribute__((address_space(1))) void*)src,
            (__attribute__((address_space(3))) void*)(smem + region + ((rowStart + (w << 3)) << 7)),
            16, 0, 0);
    };

    v4i acc[8][4] = {};
    v4i aF[4][2], bF0[2][2], bF1[2][2];

    const int KT = K / BKB;   // 32

    // prologue: stage tile 0 into buf0 in steady-state order
    STAGE(aT0, 0,     0);   STAGE(aT0, 0,     64);    // hA0
    STAGE(bT0, 32768, 0);   STAGE(bT0, 32768, 64);    // hB0
    STAGE(bT0, 32768, 128); STAGE(bT0, 32768, 192);   // hB1
    STAGE(aT0, 0,     128); STAGE(aT0, 0,     192);   // hA1
    asm volatile("s_waitcnt vmcnt(4)" ::: "memory");   // hA0,hB0 landed
    __builtin_amdgcn_s_barrier();
    __builtin_amdgcn_sched_barrier(0);

    for (int kt = 0; kt < KT; ++kt) {
        const int Ab  = (kt & 1) * 65536;
        const int Bb  = Ab + 32768;
        const int nAb = ((kt & 1) ^ 1) * 65536;
        const int nBb = nAb + 32768;
        const bool pf = (kt + 1 < KT);
        const int8_t* aTn = aT0 + (size_t)(kt + 1) * BKB;
        const int8_t* bTn = bT0 + (size_t)(kt + 1) * BKB;

        // ---------------- P0: read A-lo + B-lo; stage hA0(next); MFMA (lo,lo)
#pragma unroll
        for (int i = 0; i < 4; ++i) {
            aF[i][0] = *(const v4i*)(smem + Ab + aRB + i * 2048 + chnk0);
            aF[i][1] = *(const v4i*)(smem + Ab + aRB + i * 2048 + chnk1);
        }
#pragma unroll
        for (int j = 0; j < 2; ++j) {
            bF0[j][0] = *(const v4i*)(smem + Bb + bRB + j * 2048 + chnk0);
            bF0[j][1] = *(const v4i*)(smem + Bb + bRB + j * 2048 + chnk1);
        }
        if (pf) { STAGE(aTn, nAb, 0); STAGE(aTn, nAb, 64); }
        __builtin_amdgcn_s_barrier();
        asm volatile("s_waitcnt lgkmcnt(0)" ::: "memory");
        __builtin_amdgcn_sched_barrier(0);
        __builtin_amdgcn_s_setprio(1);
#pragma unroll
        for (int i = 0; i < 4; ++i)
#pragma unroll
            for (int j = 0; j < 2; ++j) {
                acc[i][j] = MFMA(aF[i][0], bF0[j][0], acc[i][j], 0, 0, 0);
                acc[i][j] = MFMA(aF[i][1], bF0[j][1], acc[i][j], 0, 0, 0);
            }
        __builtin_amdgcn_s_setprio(0);
        asm volatile("s_waitcnt vmcnt(4)" ::: "memory");  // hB1(kt) landed
        __builtin_amdgcn_s_barrier();
        __builtin_amdgcn_sched_barrier(0);

        // ---------------- P1: read B-hi; stage hB0(next); MFMA (lo,hi)
#pragma unroll
        for (int j = 0; j < 2; ++j) {
            bF1[j][0] = *(const v4i*)(smem + Bb + bRB + 16384 + j * 2048 + chnk0);
            bF1[j][1] = *(const v4i*)(smem + Bb + bRB + 16384 + j * 2048 + chnk1);
        }
        if (pf) { STAGE(bTn, nBb, 0); STAGE(bTn, nBb, 64); }
        __builtin_amdgcn_s_barrier();
        asm volatile("s_waitcnt lgkmcnt(0)" ::: "memory");
        __builtin_amdgcn_sched_barrier(0);
        __builtin_amdgcn_s_setprio(1);
#pragma unroll
        for (int i = 0; i < 4; ++i)
#pragma unroll
            for (int j = 0; j < 2; ++j) {
                acc[i][2 + j] = MFMA(aF[i][0], bF1[j][0], acc[i][2 + j], 0, 0, 0);
                acc[i][2 + j] = MFMA(aF[i][1], bF1[j][1], acc[i][2 + j], 0, 0, 0);
            }
        __builtin_amdgcn_s_setprio(0);
        asm volatile("s_waitcnt vmcnt(4)" ::: "memory");  // hA1(kt) landed
        __builtin_amdgcn_s_barrier();
        __builtin_amdgcn_sched_barrier(0);

        // ---------------- P2: read A-hi; stage hB1(next); MFMA (hi,lo)
#pragma unroll
        for (int i = 0; i < 4; ++i) {
            aF[i][0] = *(const v4i*)(smem + Ab + aRB + 16384 + i * 2048 + chnk0);
            aF[i][1] = *(const v4i*)(smem + Ab + aRB + 16384 + i * 2048 + chnk1);
        }
        if (pf) { STAGE(bTn, nBb, 128); STAGE(bTn, nBb, 192); }
        __builtin_amdgcn_s_barrier();
        asm volatile("s_waitcnt lgkmcnt(0)" ::: "memory");
        __builtin_amdgcn_sched_barrier(0);
        __builtin_amdgcn_s_setprio(1);
#pragma unroll
        for (int i = 0; i < 4; ++i)
#pragma unroll
            for (int j = 0; j < 2; ++j) {
                acc[4 + i][j] = MFMA(aF[i][0], bF0[j][0], acc[4 + i][j], 0, 0, 0);
                acc[4 + i][j] = MFMA(aF[i][1], bF0[j][1], acc[4 + i][j], 0, 0, 0);
            }
        __builtin_amdgcn_s_setprio(0);
        __builtin_amdgcn_s_barrier();                     // no vmcnt: P3 needs nothing new
        __builtin_amdgcn_sched_barrier(0);

        // ---------------- P3: stage hA1(next); MFMA (hi,hi)
        if (pf) { STAGE(aTn, nAb, 128); STAGE(aTn, nAb, 192); }
        __builtin_amdgcn_s_barrier();
        __builtin_amdgcn_sched_barrier(0);
        __builtin_amdgcn_s_setprio(1);
#pragma unroll
        for (int i = 0; i < 4; ++i)
#pragma unroll
            for (int j = 0; j < 2; ++j) {
                acc[4 + i][2 + j] = MFMA(aF[i][0], bF1[j][0], acc[4 + i][2 + j], 0, 0, 0);
                acc[4 + i][2 + j] = MFMA(aF[i][1], bF1[j][1], acc[4 + i][2 + j], 0, 0, 0);
            }
        __builtin_amdgcn_s_setprio(0);
        asm volatile("s_waitcnt vmcnt(4)" ::: "memory");  // hA0,hB0(kt+1) landed
        __builtin_amdgcn_s_barrier();
        __builtin_amdgcn_sched_barrier(0);
    }

    // ---------------- epilogue: dequant + bias, C/D layout col=lane&15,row=(lane>>4)*4+reg
    const int rowb = (lane >> 4) << 2;
    const int col  = lane & 15;
    float wsv[4], bv[4];
#pragma unroll
    for (int j = 0; j < 4; ++j) {
        const int n = bn * BN + ((j >> 1) << 7) + (wcol << 5) + ((j & 1) << 4) + col;
        wsv[j] = ws[n];
        bv[j]  = bias[n];
    }
#pragma unroll
    for (int i = 0; i < 8; ++i) {
        const int mbase = bm * BM + ((i >> 2) << 7) + (wrow << 6) + ((i & 3) << 4) + rowb;
#pragma unroll
        for (int r = 0; r < 4; ++r) {
            const int m = mbase + r;
            const float xsm = xs[m];
            float* yrow = Y + (size_t)m * N;
#pragma unroll
            for (int j = 0; j < 4; ++j) {
                const int n = bn * BN + ((j >> 1) << 7) + (wcol << 5) + ((j & 1) << 4) + col;
                yrow[n] = (float)acc[i][j][r] * xsm * wsv[j] + bv[j];
            }
        }
    }
}

// ---------------------------------------------------------------------------
extern "C" void kernel_launch(void* const* d_in, const int* in_sizes, int n_in,
                              void* d_out, int out_size, void* d_ws, size_t ws_size,
                              hipStream_t stream) {
    const float* X    = (const float*)d_in[0];
    const float* W    = (const float*)d_in[1];
    const float* bias = (const float*)d_in[2];
    const float* ss   = (const float*)d_in[3];

    const int DIN  = in_sizes[3];              // 4096
    const int DOUT = in_sizes[2];              // 4096
    const int M    = in_sizes[0] / DIN;        // 8192

    int8_t* Xq = (int8_t*)d_ws;
    int8_t* Wq = Xq + (size_t)M * DIN;
    float*  xs = (float*)(Wq + (size_t)DOUT * DIN);
    float*  ws = xs + M;
    float*  Y  = (float*)d_out;

    xquant_kernel<<<M,    256, 0, stream>>>(X, ss, Xq, xs, DIN);
    wquant_kernel<<<DOUT, 256, 0, stream>>>(W, ss, Wq, ws, DIN);
    gemm_i8_kernel<<<(M / BM) * (DOUT / BN), 512, 0, stream>>>(Xq, Wq, xs, ws, bias, Y, M, DOUT, DIN);
}